// Round 1
// baseline (954.377 us; speedup 1.0000x reference)
//
#include <hip/hip_runtime.h>
#include <math.h>

#define B_ 8
#define T_ 96
#define L_ 128
#define D_ 256
#define H_ 2
#define HD_ 128
#define F_ 10
#define DFF_ 1024
#define BL_ 1024
#define M_ 98304
#define SCALE_ 0.08838834764831845f

typedef __attribute__((ext_vector_type(4))) float f32x4;
typedef __attribute__((ext_vector_type(8))) short bf16x8;
typedef __attribute__((ext_vector_type(4))) unsigned short u16x4;

__device__ __forceinline__ unsigned short f2bf(float f) {
  union { float f; unsigned int u; } v; v.f = f;
  unsigned int r = v.u + 0x7fffu + ((v.u >> 16) & 1u);
  return (unsigned short)(r >> 16);
}
__device__ __forceinline__ float bf2f(unsigned short s) {
  union { unsigned int u; float f; } v; v.u = ((unsigned int)s) << 16;
  return v.f;
}
__device__ __forceinline__ f32x4 mfma16(bf16x8 a, bf16x8 b, f32x4 c) {
  return __builtin_amdgcn_mfma_f32_16x16x32_bf16(a, b, c, 0, 0, 0);
}
__device__ __forceinline__ float wave_sum(float v) {
  #pragma unroll
  for (int m = 1; m < 64; m <<= 1) v += __shfl_xor(v, m, 64);
  return v;
}

// ---------------- weight f32 -> bf16 ----------------
__global__ void f2bf_kernel(const float* __restrict__ src,
                            unsigned short* __restrict__ dst, int n) {
  int i = blockIdx.x * 256 + threadIdx.x;
  if (i < n) dst[i] = f2bf(src[i]);
}

// ---------------- fused MLP + residual + LN ----------------
// MODE 1: A = gather(x f32), residual = x,  out = x_proj bf16 [M,256], LN(gA,bA)
// MODE 2: A = recv bf16 [M,256], residual = x_proj bf16,
//         out = f32 scattered to [B,T,L,D], LN(gA,bA) then LN(gB,bB)
template<int MODE>
__launch_bounds__(256, 2)
__global__ void mlp_ln_kernel(
    const float* __restrict__ xin,
    const unsigned short* __restrict__ ain_bf,
    const unsigned short* __restrict__ res_bf,
    const unsigned short* __restrict__ w1,   // [DFF,256] bf16 (rows n, k contig)
    const float* __restrict__ b1,            // [DFF]
    const unsigned short* __restrict__ w2,   // [256,DFF] bf16
    const float* __restrict__ b2,            // [256]
    const float* __restrict__ gA, const float* __restrict__ bA,
    const float* __restrict__ gB, const float* __restrict__ bB,
    unsigned short* __restrict__ out_bf,
    float* __restrict__ out_f32)
{
  __shared__ __align__(16) unsigned char smem[65536];
  unsigned short* As = (unsigned short*)smem;            // [64][256] bf16 swz
  unsigned short* Hs = (unsigned short*)(smem + 32768);  // [64][256] bf16 swz
  float* Ys = (float*)smem;                              // [64][256] f32 (overlay)

  const int tid = threadIdx.x;
  const int m0 = blockIdx.x * 64;

  // ---- stage A tile (64 rows x 256) as bf16, XOR-swizzled ----
  #pragma unroll
  for (int it = 0; it < 8; ++it) {
    int u = tid + it * 256;
    int row = u >> 5, k = (u & 31) * 8;
    bf16x8 v;
    if constexpr (MODE == 1) {
      int m = m0 + row;
      int bb_ = m / (L_ * T_);
      int rem = m - bb_ * (L_ * T_);
      int li = rem / T_;
      int tt = rem - li * T_;
      const float* p = xin + (((size_t)((bb_ * T_ + tt) * L_ + li)) << 8) + k;
      #pragma unroll
      for (int i = 0; i < 8; ++i) v[i] = (short)f2bf(p[i]);
    } else {
      v = *(const bf16x8*)(ain_bf + (size_t)(m0 + row) * D_ + k);
    }
    *(bf16x8*)(As + ((row * D_ + k) ^ ((row & 7) << 3))) = v;
  }
  __syncthreads();

  const int wid = tid >> 6;
  const int lane = tid & 63;
  const int lr = lane & 15;
  const int lk = lane >> 4;

  f32x4 acc_y[4][4];
  #pragma unroll
  for (int nf = 0; nf < 4; ++nf) {
    float bb = b2[wid * 64 + nf * 16 + lr];
    #pragma unroll
    for (int mf = 0; mf < 4; ++mf) acc_y[mf][nf] = (f32x4){bb, bb, bb, bb};
  }

  #pragma unroll 1
  for (int c = 0; c < 4; ++c) {
    // GEMM1: hc[64][256] = A @ w1_chunk^T + b1
    f32x4 acc_h[4][4];
    #pragma unroll
    for (int nf = 0; nf < 4; ++nf) {
      float bb = b1[c * 256 + wid * 64 + nf * 16 + lr];
      #pragma unroll
      for (int mf = 0; mf < 4; ++mf) acc_h[mf][nf] = (f32x4){bb, bb, bb, bb};
    }
    #pragma unroll
    for (int ks = 0; ks < 8; ++ks) {
      bf16x8 a[4], bfr[4];
      #pragma unroll
      for (int mf = 0; mf < 4; ++mf) {
        int row = mf * 16 + lr;
        a[mf] = *(const bf16x8*)(As + ((row * D_ + ks * 32 + lk * 8) ^ ((row & 7) << 3)));
      }
      #pragma unroll
      for (int nf = 0; nf < 4; ++nf) {
        int n1 = c * 256 + wid * 64 + nf * 16 + lr;
        bfr[nf] = *(const bf16x8*)(w1 + (size_t)n1 * D_ + ks * 32 + lk * 8);
      }
      #pragma unroll
      for (int mf = 0; mf < 4; ++mf)
        #pragma unroll
        for (int nf = 0; nf < 4; ++nf)
          acc_h[mf][nf] = mfma16(a[mf], bfr[nf], acc_h[mf][nf]);
    }
    // gelu -> Hs (bf16, swizzled)
    #pragma unroll
    for (int mf = 0; mf < 4; ++mf)
      #pragma unroll
      for (int nf = 0; nf < 4; ++nf)
        #pragma unroll
        for (int j = 0; j < 4; ++j) {
          int row = mf * 16 + lk * 4 + j;
          int col = wid * 64 + nf * 16 + lr;
          float v = acc_h[mf][nf][j];
          float g = 0.5f * v * (1.0f + erff(v * 0.70710678118654752f));
          Hs[(row * D_ + col) ^ ((row & 7) << 3)] = f2bf(g);
        }
    __syncthreads();
    // GEMM2: acc_y += gelu_h @ w2_chunk^T
    #pragma unroll
    for (int ks = 0; ks < 8; ++ks) {
      bf16x8 a[4], bfr[4];
      #pragma unroll
      for (int mf = 0; mf < 4; ++mf) {
        int row = mf * 16 + lr;
        a[mf] = *(const bf16x8*)(Hs + ((row * D_ + ks * 32 + lk * 8) ^ ((row & 7) << 3)));
      }
      #pragma unroll
      for (int nf = 0; nf < 4; ++nf) {
        int n2 = wid * 64 + nf * 16 + lr;
        bfr[nf] = *(const bf16x8*)(w2 + (size_t)n2 * DFF_ + c * 256 + ks * 32 + lk * 8);
      }
      #pragma unroll
      for (int mf = 0; mf < 4; ++mf)
        #pragma unroll
        for (int nf = 0; nf < 4; ++nf)
          acc_y[mf][nf] = mfma16(a[mf], bfr[nf], acc_y[mf][nf]);
    }
    __syncthreads();
  }

  // ---- epilogue: frags -> Ys f32 ----
  #pragma unroll
  for (int mf = 0; mf < 4; ++mf)
    #pragma unroll
    for (int nf = 0; nf < 4; ++nf)
      #pragma unroll
      for (int j = 0; j < 4; ++j) {
        int row = mf * 16 + lk * 4 + j;
        int col = wid * 64 + nf * 16 + lr;
        Ys[row * 256 + col] = acc_y[mf][nf][j];
      }
  __syncthreads();

  const float4 gAv = *(const float4*)(gA + lane * 4);
  const float4 bAv = *(const float4*)(bA + lane * 4);
  float4 gBv = {0.f, 0.f, 0.f, 0.f}, bBv = {0.f, 0.f, 0.f, 0.f};
  if constexpr (MODE == 2) {
    gBv = *(const float4*)(gB + lane * 4);
    bBv = *(const float4*)(bB + lane * 4);
  }

  #pragma unroll 1
  for (int i = 0; i < 16; ++i) {
    int row = wid * 16 + i;
    int m = m0 + row;
    int bb_ = m / (L_ * T_);
    int rem = m - bb_ * (L_ * T_);
    int li = rem / T_;
    int tt = rem - li * T_;
    size_t xoff = ((size_t)((bb_ * T_ + tt) * L_ + li)) << 8;
    const float* yr = Ys + row * 256 + lane * 4;
    float v0 = yr[0], v1 = yr[1], v2 = yr[2], v3 = yr[3];
    if constexpr (MODE == 1) {
      float4 r = *(const float4*)(xin + xoff + lane * 4);
      v0 += r.x; v1 += r.y; v2 += r.z; v3 += r.w;
    } else {
      u16x4 r = *(const u16x4*)(res_bf + (size_t)m * D_ + lane * 4);
      v0 += bf2f(r[0]); v1 += bf2f(r[1]); v2 += bf2f(r[2]); v3 += bf2f(r[3]);
    }
    float s = v0 + v1 + v2 + v3;
    float q = v0 * v0 + v1 * v1 + v2 * v2 + v3 * v3;
    s = wave_sum(s); q = wave_sum(q);
    float mean = s * (1.0f / 256.0f);
    float var = q * (1.0f / 256.0f) - mean * mean;
    float rstd = rsqrtf(var + 1e-5f);
    float u0 = (v0 - mean) * rstd * gAv.x + bAv.x;
    float u1 = (v1 - mean) * rstd * gAv.y + bAv.y;
    float u2 = (v2 - mean) * rstd * gAv.z + bAv.z;
    float u3 = (v3 - mean) * rstd * gAv.w + bAv.w;
    if constexpr (MODE == 1) {
      u16x4 o;
      o[0] = f2bf(u0); o[1] = f2bf(u1); o[2] = f2bf(u2); o[3] = f2bf(u3);
      *(u16x4*)(out_bf + (size_t)m * D_ + lane * 4) = o;
    } else {
      float s2 = u0 + u1 + u2 + u3;
      float q2 = u0 * u0 + u1 * u1 + u2 * u2 + u3 * u3;
      s2 = wave_sum(s2); q2 = wave_sum(q2);
      float mean2 = s2 * (1.0f / 256.0f);
      float var2 = q2 * (1.0f / 256.0f) - mean2 * mean2;
      float rstd2 = rsqrtf(var2 + 1e-5f);
      float4 o;
      o.x = (u0 - mean2) * rstd2 * gBv.x + bBv.x;
      o.y = (u1 - mean2) * rstd2 * gBv.y + bBv.y;
      o.z = (u2 - mean2) * rstd2 * gBv.z + bBv.z;
      o.w = (u3 - mean2) * rstd2 * gBv.w + bBv.w;
      *(float4*)(out_f32 + xoff + lane * 4) = o;
    }
  }
}

// ---------------- projection GEMM (N=256, K=256) + bias + scatter ----------------
// WHICH 0/1/2: A = x_proj bf16 [M,256] -> out [BL][H][T][HD]
// WHICH 3:     A = router f32 [L*F,256] -> out [L][H][F][HD]
template<int WHICH>
__launch_bounds__(256, 2)
__global__ void proj_kernel(const unsigned short* __restrict__ ain,
                            const float* __restrict__ ain_f,
                            const unsigned short* __restrict__ wbf,  // [256,256] bf16
                            const float* __restrict__ bias,
                            unsigned short* __restrict__ outp)
{
  __shared__ __align__(16) unsigned short As[64 * 256];
  const int tid = threadIdx.x;
  const int m0 = blockIdx.x * 64;
  #pragma unroll
  for (int it = 0; it < 8; ++it) {
    int u = tid + it * 256;
    int row = u >> 5, k = (u & 31) * 8;
    bf16x8 v;
    if constexpr (WHICH == 3) {
      const float* p = ain_f + (size_t)(m0 + row) * D_ + k;
      #pragma unroll
      for (int i = 0; i < 8; ++i) v[i] = (short)f2bf(p[i]);
    } else {
      v = *(const bf16x8*)(ain + (size_t)(m0 + row) * D_ + k);
    }
    *(bf16x8*)(As + ((row * D_ + k) ^ ((row & 7) << 3))) = v;
  }
  __syncthreads();
  const int wid = tid >> 6, lane = tid & 63, lr = lane & 15, lk = lane >> 4;
  f32x4 acc[4][4];
  #pragma unroll
  for (int nf = 0; nf < 4; ++nf) {
    float bb = bias[wid * 64 + nf * 16 + lr];
    #pragma unroll
    for (int mf = 0; mf < 4; ++mf) acc[mf][nf] = (f32x4){bb, bb, bb, bb};
  }
  #pragma unroll
  for (int ks = 0; ks < 8; ++ks) {
    bf16x8 a[4], bfr[4];
    #pragma unroll
    for (int mf = 0; mf < 4; ++mf) {
      int row = mf * 16 + lr;
      a[mf] = *(const bf16x8*)(As + ((row * D_ + ks * 32 + lk * 8) ^ ((row & 7) << 3)));
    }
    #pragma unroll
    for (int nf = 0; nf < 4; ++nf) {
      int n = wid * 64 + nf * 16 + lr;
      bfr[nf] = *(const bf16x8*)(wbf + (size_t)n * D_ + ks * 32 + lk * 8);
    }
    #pragma unroll
    for (int mf = 0; mf < 4; ++mf)
      #pragma unroll
      for (int nf = 0; nf < 4; ++nf)
        acc[mf][nf] = mfma16(a[mf], bfr[nf], acc[mf][nf]);
  }
  #pragma unroll
  for (int mf = 0; mf < 4; ++mf)
    #pragma unroll
    for (int nf = 0; nf < 4; ++nf)
      #pragma unroll
      for (int j = 0; j < 4; ++j) {
        int m = m0 + mf * 16 + lk * 4 + j;
        int n = wid * 64 + nf * 16 + lr;
        unsigned short val = f2bf(acc[mf][nf][j]);
        int h = n >> 7, hd = n & 127;
        if constexpr (WHICH < 3) {
          int bl = m / T_, t = m - bl * T_;
          outp[(size_t)((bl * 2 + h) * T_ + t) * HD_ + hd] = val;
        } else {
          int li = m / F_, f = m - li * F_;
          outp[(size_t)((li * 2 + h) * F_ + f) * HD_ + hd] = val;
        }
      }
}

// ---------------- sender attention: router queries over windowed keys ----------------
__global__ void sender_kernel(const unsigned short* __restrict__ Kb,
                              const unsigned short* __restrict__ Vb,
                              const unsigned short* __restrict__ Rp,
                              unsigned short* __restrict__ Sd)
{
  __shared__ float Ks[15 * 128];
  __shared__ float Vs[15 * 128];
  const int bh = blockIdx.x;             // bl*2 + h
  const int l = (bh >> 1) & (L_ - 1);
  const int h = bh & 1;
  const int tid = threadIdx.x;
  for (int u = tid; u < 15 * 128; u += 256) {
    Ks[u] = bf2f(Kb[(size_t)bh * T_ * HD_ + u]);
    Vs[u] = bf2f(Vb[(size_t)bh * T_ * HD_ + u]);
  }
  __syncthreads();
  const int wid = tid >> 6, lane = tid & 63;
  const int d0 = lane * 2;
  for (int f = wid; f < F_; f += 4) {
    float q0 = bf2f(Rp[(size_t)((l * 2 + h) * F_ + f) * HD_ + d0]);
    float q1 = bf2f(Rp[(size_t)((l * 2 + h) * F_ + f) * HD_ + d0 + 1]);
    float sc[11];
    #pragma unroll
    for (int jj = 0; jj < 11; ++jj) {
      int j = f - 5 + jj;
      int jc = j < 0 ? 0 : j;
      float p = q0 * Ks[jc * 128 + d0] + q1 * Ks[jc * 128 + d0 + 1];
      float r = wave_sum(p) * SCALE_;
      r = fminf(fmaxf(r, -10000.0f), 10000.0f);
      sc[jj] = (j >= 0) ? r : -1e30f;
    }
    float mx = sc[0];
    #pragma unroll
    for (int jj = 1; jj < 11; ++jj) mx = fmaxf(mx, sc[jj]);
    float pr[11], se = 0.0f;
    #pragma unroll
    for (int jj = 0; jj < 11; ++jj) { pr[jj] = __expf(sc[jj] - mx); se += pr[jj]; }
    float inv = 1.0f / se;
    float o0 = 0.0f, o1 = 0.0f;
    #pragma unroll
    for (int jj = 0; jj < 11; ++jj) {
      int j = f - 5 + jj;
      int jc = j < 0 ? 0 : j;
      float w = pr[jj] * inv;
      o0 += w * Vs[jc * 128 + d0];
      o1 += w * Vs[jc * 128 + d0 + 1];
    }
    unsigned int pk = (unsigned int)f2bf(o0) | ((unsigned int)f2bf(o1) << 16);
    *(unsigned int*)(Sd + (size_t)(bh * F_ + f) * HD_ + d0) = pk;
  }
}

// ---------------- recv attention: 96 queries over 10 senders ----------------
__global__ void recv_kernel(const unsigned short* __restrict__ Qb,
                            const unsigned short* __restrict__ Sd,
                            unsigned short* __restrict__ Rv)
{
  __shared__ float Ss[F_ * 128];
  const int bh = blockIdx.x;
  const int bl = bh >> 1, h = bh & 1;
  const int tid = threadIdx.x;
  for (int u = tid; u < F_ * 128; u += 256) Ss[u] = bf2f(Sd[(size_t)bh * F_ * HD_ + u]);
  __syncthreads();
  const int wid = tid >> 6, lane = tid & 63;
  const int d0 = lane * 2;
  for (int t = wid; t < T_; t += 4) {
    float q0 = bf2f(Qb[(size_t)(bh * T_ + t) * HD_ + d0]);
    float q1 = bf2f(Qb[(size_t)(bh * T_ + t) * HD_ + d0 + 1]);
    float sc[10];
    #pragma unroll
    for (int j = 0; j < 10; ++j) {
      float p = q0 * Ss[j * 128 + d0] + q1 * Ss[j * 128 + d0 + 1];
      float r = wave_sum(p) * SCALE_;
      r = fminf(fmaxf(r, -10000.0f), 10000.0f);
      bool allowed = (t >= 10) || ((j >= t - 5) && (j <= t + 5));
      sc[j] = allowed ? r : -1e30f;
    }
    float mx = sc[0];
    #pragma unroll
    for (int j = 1; j < 10; ++j) mx = fmaxf(mx, sc[j]);
    float pr[10], se = 0.0f;
    #pragma unroll
    for (int j = 0; j < 10; ++j) { pr[j] = __expf(sc[j] - mx); se += pr[j]; }
    float inv = 1.0f / se;
    float o0 = 0.0f, o1 = 0.0f;
    #pragma unroll
    for (int j = 0; j < 10; ++j) {
      float w = pr[j] * inv;
      o0 += w * Ss[j * 128 + d0];
      o1 += w * Ss[j * 128 + d0 + 1];
    }
    unsigned int pk = (unsigned int)f2bf(o0) | ((unsigned int)f2bf(o1) << 16);
    *(unsigned int*)(Rv + (size_t)(bl * T_ + t) * D_ + h * HD_ + d0) = pk;
  }
}

extern "C" void kernel_launch(void* const* d_in, const int* in_sizes, int n_in,
                              void* d_out, int out_size, void* d_ws, size_t ws_size,
                              hipStream_t stream) {
  const float* x      = (const float*)d_in[0];
  const float* router = (const float*)d_in[1];
  const float* Wr     = (const float*)d_in[2];
  const float* br     = (const float*)d_in[3];
  const float* Wk     = (const float*)d_in[4];
  const float* bk     = (const float*)d_in[5];
  const float* Wv     = (const float*)d_in[6];
  const float* bv     = (const float*)d_in[7];
  const float* Wq     = (const float*)d_in[8];
  const float* bq     = (const float*)d_in[9];
  const float* g1     = (const float*)d_in[10];
  const float* beta1  = (const float*)d_in[11];
  const float* g2     = (const float*)d_in[12];
  const float* beta2  = (const float*)d_in[13];
  const float* g3     = (const float*)d_in[14];
  const float* beta3  = (const float*)d_in[15];
  const float* m1_w1  = (const float*)d_in[16];
  const float* m1_b1  = (const float*)d_in[17];
  const float* m1_w2  = (const float*)d_in[18];
  const float* m1_b2  = (const float*)d_in[19];
  const float* m2_w1  = (const float*)d_in[20];
  const float* m2_b1  = (const float*)d_in[21];
  const float* m2_w2  = (const float*)d_in[22];
  const float* m2_b2  = (const float*)d_in[23];
  float* out = (float*)d_out;

  char* ws = (char*)d_ws;
  unsigned short* w1a   = (unsigned short*)(ws + 0);          // m1_w1 bf16 [1024,256]
  unsigned short* w1b   = (unsigned short*)(ws + 524288);     // m1_w2 bf16 [256,1024]
  unsigned short* w2a   = (unsigned short*)(ws + 1048576);    // m2_w1
  unsigned short* w2b   = (unsigned short*)(ws + 1572864);    // m2_w2
  unsigned short* wkb   = (unsigned short*)(ws + 2097152);
  unsigned short* wvb   = (unsigned short*)(ws + 2228224);
  unsigned short* wqb   = (unsigned short*)(ws + 2359296);
  unsigned short* wrb   = (unsigned short*)(ws + 2490368);
  unsigned short* xproj = (unsigned short*)(ws + 2621440);    // [M,256]
  unsigned short* kbuf  = (unsigned short*)(ws + 52953088);   // [BL,H,T,HD] (recv aliases)
  unsigned short* vbuf  = (unsigned short*)(ws + 103284736);
  unsigned short* qbuf  = (unsigned short*)(ws + 153616384);
  unsigned short* sdbuf = (unsigned short*)(ws + 203948032);  // [BL,H,F,HD]
  unsigned short* rpbuf = (unsigned short*)(ws + 209190912);  // [L,H,F,HD]

  f2bf_kernel<<<1024, 256, 0, stream>>>(m1_w1, w1a, 262144);
  f2bf_kernel<<<1024, 256, 0, stream>>>(m1_w2, w1b, 262144);
  f2bf_kernel<<<1024, 256, 0, stream>>>(m2_w1, w2a, 262144);
  f2bf_kernel<<<1024, 256, 0, stream>>>(m2_w2, w2b, 262144);
  f2bf_kernel<<<256, 256, 0, stream>>>(Wk, wkb, 65536);
  f2bf_kernel<<<256, 256, 0, stream>>>(Wv, wvb, 65536);
  f2bf_kernel<<<256, 256, 0, stream>>>(Wq, wqb, 65536);
  f2bf_kernel<<<256, 256, 0, stream>>>(Wr, wrb, 65536);

  mlp_ln_kernel<1><<<M_ / 64, 256, 0, stream>>>(
      x, nullptr, nullptr, w1a, m1_b1, w1b, m1_b2,
      g1, beta1, nullptr, nullptr, xproj, nullptr);

  proj_kernel<0><<<M_ / 64, 256, 0, stream>>>(xproj, nullptr, wkb, bk, kbuf);
  proj_kernel<1><<<M_ / 64, 256, 0, stream>>>(xproj, nullptr, wvb, bv, vbuf);
  proj_kernel<2><<<M_ / 64, 256, 0, stream>>>(xproj, nullptr, wqb, bq, qbuf);
  proj_kernel<3><<<(L_ * F_) / 64, 256, 0, stream>>>(nullptr, router, wrb, br, rpbuf);

  sender_kernel<<<BL_ * H_, 256, 0, stream>>>(kbuf, vbuf, rpbuf, sdbuf);

  unsigned short* recv = kbuf;  // K dead after sender_kernel; alias
  recv_kernel<<<BL_ * H_, 256, 0, stream>>>(qbuf, sdbuf, recv);

  mlp_ln_kernel<2><<<M_ / 64, 256, 0, stream>>>(
      nullptr, recv, xproj, w2a, m2_b1, w2b, m2_b2,
      g2, beta2, g3, beta3, nullptr, out);
}